// Round 12
// baseline (200.212 us; speedup 1.0000x reference)
//
#include <hip/hip_runtime.h>
#include <hip/hip_fp16.h>
#include <cstdint>

#define N_NODES 50000
#define N_EDGES 800000
#define D 128
#define NCH 64                                        // edge chunks
#define CH_E 12500                                    // edges per chunk (64*12500 = N_EDGES)
#define NBINS 782                                     // coarse bins (64 nodes each)
#define PCAP 48                                       // per-(chunk,bin) capacity: mean 16, +8 sigma
#define SCAP 64                                       // col slots per node
#define KVSTR 256                                     // halves per node in KV: 128 K + 128 V
#define QKV_BLOCKS ((N_NODES + 63) / 64)              // 782

typedef _Float16 half8 __attribute__((ext_vector_type(8)));
typedef _Float16 half2_t __attribute__((ext_vector_type(2)));
typedef __attribute__((ext_vector_type(4))) float float4v;
typedef unsigned short ushort_t;
typedef unsigned int uint_t;

__device__ __forceinline__ ushort_t f2h(float f) {
    return __half_as_ushort(__float2half(f));   // RNE hardware cvt
}
__device__ __forceinline__ half2_t u2h2(unsigned u) {
    union { unsigned u; half2_t h; } c; c.u = u; return c.h;
}

// ---------------------------------------------------------------------------
// k1: blocks 0..2 repack W fp32 -> fp16 B-fragment order; blocks 3..66 =
//     single-pass histogram+scatter per chunk. Fixed per-(chunk,bin)
//     capacity PCAP makes positions deterministic -> NO scan kernel, NO
//     prefix arrays, NO device atomics. Rank comes from the LDS counter.
// ---------------------------------------------------------------------------
__global__ __launch_bounds__(256) void scatter_prep(
    const float* __restrict__ Wq, const float* __restrict__ Wk,
    const float* __restrict__ Wv, ushort_t* __restrict__ WpAll,
    const int* __restrict__ rows, const int* __restrict__ cols,
    int* __restrict__ sorted, int* __restrict__ cnt_g)
{
    __shared__ int hist[NBINS];
    if (blockIdx.x < 3) {
        const float* W = (blockIdx.x == 0) ? Wq : (blockIdx.x == 1) ? Wk : Wv;
        ushort_t* Wp = WpAll + blockIdx.x * (D * D);
        for (int i = threadIdx.x; i < D * D; i += 256) {
            const int j    = i & 7;
            const int lane = (i >> 3) & 63;
            const int f    = i >> 9;
            const int kk = f >> 3, nt = f & 7;
            const int k = kk * 32 + (lane >> 4) * 8 + j;
            const int n = (lane & 15) * 8 + nt;     // permuted column order
            Wp[i] = f2h(W[k * D + n]);
        }
        return;
    }
    const int c = blockIdx.x - 3;
    for (int t = threadIdx.x; t < NBINS; t += 256) hist[t] = 0;
    __syncthreads();
    const int e0 = c * CH_E;
    for (int i = threadIdx.x; i < CH_E; i += 256) {
        const int row = rows[e0 + i];
        const int col = cols[e0 + i];
        const int bin = row >> 6;
        const int r = atomicAdd(&hist[bin], 1);      // LDS-scope atomic
        if (r < PCAP)
            sorted[((size_t)bin * NCH + c) * PCAP + r] = ((row & 63) << 16) | col;
    }
    __syncthreads();
    for (int t = threadIdx.x; t < NBINS; t += 256)
        cnt_g[t * NCH + c] = min(hist[t], PCAP);     // fully written every run
}

// ---------------------------------------------------------------------------
// k2: blocks [0, QKV_BLOCKS): MFMA QKV GEMM (needs only k1's W-repack).
//     blocks [QKV_BLOCKS, +NBINS): per-bin list build (needs only k1's
//     sorted/cnt_g). The two populations overlap on the machine.
// ---------------------------------------------------------------------------
__global__ __launch_bounds__(256) void gemm_build(
    const float* __restrict__ emb, const ushort_t* __restrict__ WpAll,
    ushort_t* __restrict__ Qh, ushort_t* __restrict__ KVh,
    const int* __restrict__ sorted, const int* __restrict__ cnt_g,
    int* __restrict__ cnt, ushort_t* __restrict__ slots)
{
    if (blockIdx.x >= QKV_BLOCKS) {
        __shared__ ushort_t sl[64 * SCAP];   // 8 KB
        __shared__ int scnt[64];
        __shared__ int cl[NCH];

        const int b = blockIdx.x - QKV_BLOCKS;
        if (threadIdx.x < 64) {
            scnt[threadIdx.x] = 0;
            cl[threadIdx.x] = cnt_g[b * NCH + threadIdx.x];
        }
        __syncthreads();
        for (int t = threadIdx.x; t < NCH * PCAP; t += 256) {   // 3072 slots
            const int c = t / PCAP;
            const int r = t - c * PCAP;
            if (r < cl[c]) {
                const int p  = sorted[((size_t)b * NCH + c) * PCAP + r];
                const int rl = p >> 16;
                const int pos = atomicAdd(&scnt[rl], 1);        // LDS-scope atomic
                if (pos < SCAP) sl[rl * SCAP + pos] = (ushort_t)(p & 0xFFFF);
            }
        }
        __syncthreads();
        const int node0 = b * 64;
        const uint_t* slu = (const uint_t*)sl;
        uint_t* out_u = (uint_t*)(slots + (size_t)node0 * SCAP);
        for (int t = threadIdx.x; t < 2048; t += 256) {  // 32 uints per node
            const int node = node0 + (t >> 5);
            if (node < N_NODES) out_u[t] = slu[t];
        }
        if (threadIdx.x < 64) {
            const int node = node0 + threadIdx.x;
            if (node < N_NODES) cnt[node] = min(scnt[threadIdx.x], SCAP);
        }
        return;
    }

    const int blk  = blockIdx.x;
    const int t    = threadIdx.x;
    const int wave = t >> 6;
    const int lane = t & 63;
    const int row0 = blk * 64 + wave * 16;
    const int m    = lane & 15;
    const int q    = lane >> 4;

    // A fragments: loaded once, reused for Q,K,V
    const int arow = min(row0 + m, N_NODES - 1);
    const float* abase = emb + (size_t)arow * D + q * 8;
    half8 a[4];
    #pragma unroll
    for (int kk = 0; kk < 4; ++kk) {
        const float4 f0 = *(const float4*)(abase + kk * 32);
        const float4 f1 = *(const float4*)(abase + kk * 32 + 4);
        a[kk][0] = (_Float16)f0.x; a[kk][1] = (_Float16)f0.y;
        a[kk][2] = (_Float16)f0.z; a[kk][3] = (_Float16)f0.w;
        a[kk][4] = (_Float16)f1.x; a[kk][5] = (_Float16)f1.y;
        a[kk][6] = (_Float16)f1.z; a[kk][7] = (_Float16)f1.w;
    }

    for (int y = 0; y < 3; ++y) {
        const ushort_t* Wp = WpAll + y * (D * D);

        float4v acc[8];
        #pragma unroll
        for (int nt = 0; nt < 8; ++nt) acc[nt] = (float4v){0.f, 0.f, 0.f, 0.f};

        #pragma unroll
        for (int kk = 0; kk < 4; ++kk) {
            #pragma unroll
            for (int nt = 0; nt < 8; ++nt) {
                const half8 bfr = *(const half8*)(Wp + ((kk * 8 + nt) * 64 + lane) * 8);
                acc[nt] = __builtin_amdgcn_mfma_f32_16x16x32_f16(a[kk], bfr, acc[nt], 0, 0, 0);
            }
        }

        #pragma unroll
        for (int r = 0; r < 4; ++r) {
            const int row = row0 + q * 4 + r;
            if (row < N_NODES) {
                ushort_t pk[8];
                #pragma unroll
                for (int nt = 0; nt < 8; ++nt) pk[nt] = f2h(acc[nt][r]);
                ushort_t* dst =
                    (y == 0) ? (Qh  + (size_t)row * D + m * 8)
                  : (y == 1) ? (KVh + (size_t)row * KVSTR + m * 8)
                             : (KVh + (size_t)row * KVSTR + 128 + m * 8);
                *(int4*)dst = *(const int4*)pk;
            }
        }
    }
}

// ---------------------------------------------------------------------------
// k3: Node attention — byte-identical to r9's proven 61 µs kernel.
// One wave per node; lane owns 8 dims; 16 lanes per edge, 4 edge-groups;
// x2 unroll -> 8 edges in flight. Ushort slot line; cols via bpermute;
// K and V are one 512 B KVh record per edge.
// ---------------------------------------------------------------------------
__global__ __launch_bounds__(256) void node_attn(
    const ushort_t* __restrict__ Qh, const ushort_t* __restrict__ KVh,
    const float* __restrict__ emb,
    const int* __restrict__ cnt, const ushort_t* __restrict__ slots,
    const float* __restrict__ gam, const float* __restrict__ bet,
    float* __restrict__ out)
{
    const int node = (int)((blockIdx.x * blockDim.x + threadIdx.x) >> 6);
    if (node >= N_NODES) return;
    const int lane = threadIdx.x & 63;
    const int g    = lane >> 4;          // edge group 0..3
    const int l4   = lane & 15;          // dim-lane within edge
    const int d0   = l4 * 8;             // first of 8 owned dims

    // full slot line in registers: lane j holds col j
    const int slot = (int)slots[(size_t)node * SCAP + lane];
    const int deg  = min(cnt[node], SCAP);

    const uint4 qw = *(const uint4*)(Qh + (size_t)node * D + d0);
    const half2_t q01 = u2h2(qw.x), q23 = u2h2(qw.y);
    const half2_t q45 = u2h2(qw.z), q67 = u2h2(qw.w);

    // residual load hoisted above the loop (independent; hides latency)
    const float4 rA = *(const float4*)(emb + (size_t)node * D + d0);
    const float4 rB = *(const float4*)(emb + (size_t)node * D + d0 + 4);

    float a0=0.f,a1=0.f,a2=0.f,a3=0.f,a4=0.f,a5=0.f,a6=0.f,a7=0.f,den=0.f;

    int i = 0;
    for (; i + 8 <= deg; i += 8) {
        const int cA = __shfl(slot, i + g);
        const int cB = __shfl(slot, i + 4 + g);
        const ushort_t* kvA = KVh + (size_t)cA * KVSTR + d0;
        const ushort_t* kvB = KVh + (size_t)cB * KVSTR + d0;
        const uint4 kA = *(const uint4*)(kvA);
        const uint4 vA = *(const uint4*)(kvA + 128);
        const uint4 kB = *(const uint4*)(kvB);
        const uint4 vB = *(const uint4*)(kvB + 128);

        float pA = __builtin_amdgcn_fdot2(q01, u2h2(kA.x), 0.f, false);
        pA = __builtin_amdgcn_fdot2(q23, u2h2(kA.y), pA, false);
        pA = __builtin_amdgcn_fdot2(q45, u2h2(kA.z), pA, false);
        pA = __builtin_amdgcn_fdot2(q67, u2h2(kA.w), pA, false);
        float pB = __builtin_amdgcn_fdot2(q01, u2h2(kB.x), 0.f, false);
        pB = __builtin_amdgcn_fdot2(q23, u2h2(kB.y), pB, false);
        pB = __builtin_amdgcn_fdot2(q45, u2h2(kB.z), pB, false);
        pB = __builtin_amdgcn_fdot2(q67, u2h2(kB.w), pB, false);
        pA += __shfl_xor(pA, 1);
        pB += __shfl_xor(pB, 1);
        const float wA = __expf(fminf(10.f, fmaxf(-10.f, pA)));
        const float wB = __expf(fminf(10.f, fmaxf(-10.f, pB)));
        den += wA + wB;

        const half2_t vA01 = u2h2(vA.x), vA23 = u2h2(vA.y);
        const half2_t vA45 = u2h2(vA.z), vA67 = u2h2(vA.w);
        const half2_t vB01 = u2h2(vB.x), vB23 = u2h2(vB.y);
        const half2_t vB45 = u2h2(vB.z), vB67 = u2h2(vB.w);
        a0 += wA * (float)vA01[0] + wB * (float)vB01[0];
        a1 += wA * (float)vA01[1] + wB * (float)vB01[1];
        a2 += wA * (float)vA23[0] + wB * (float)vB23[0];
        a3 += wA * (float)vA23[1] + wB * (float)vB23[1];
        a4 += wA * (float)vA45[0] + wB * (float)vB45[0];
        a5 += wA * (float)vA45[1] + wB * (float)vB45[1];
        a6 += wA * (float)vA67[0] + wB * (float)vB67[0];
        a7 += wA * (float)vA67[1] + wB * (float)vB67[1];
    }
    for (; i < deg; i += 4) {
        const int idx = i + g;
        const int c = __shfl(slot, (idx < deg) ? idx : (deg - 1));
        const ushort_t* kv = KVh + (size_t)c * KVSTR + d0;
        const uint4 kk = *(const uint4*)(kv);
        const uint4 vv = *(const uint4*)(kv + 128);
        float p = __builtin_amdgcn_fdot2(q01, u2h2(kk.x), 0.f, false);
        p = __builtin_amdgcn_fdot2(q23, u2h2(kk.y), p, false);
        p = __builtin_amdgcn_fdot2(q45, u2h2(kk.z), p, false);
        p = __builtin_amdgcn_fdot2(q67, u2h2(kk.w), p, false);
        p += __shfl_xor(p, 1);
        float w = __expf(fminf(10.f, fmaxf(-10.f, p)));
        w = (idx < deg) ? w : 0.f;
        den += w;
        const half2_t v01 = u2h2(vv.x), v23 = u2h2(vv.y);
        const half2_t v45 = u2h2(vv.z), v67 = u2h2(vv.w);
        a0 += w * (float)v01[0]; a1 += w * (float)v01[1];
        a2 += w * (float)v23[0]; a3 += w * (float)v23[1];
        a4 += w * (float)v45[0]; a5 += w * (float)v45[1];
        a6 += w * (float)v67[0]; a7 += w * (float)v67[1];
    }

    // fold the 4 edge-groups
    a0 += __shfl_xor(a0, 16); a0 += __shfl_xor(a0, 32);
    a1 += __shfl_xor(a1, 16); a1 += __shfl_xor(a1, 32);
    a2 += __shfl_xor(a2, 16); a2 += __shfl_xor(a2, 32);
    a3 += __shfl_xor(a3, 16); a3 += __shfl_xor(a3, 32);
    a4 += __shfl_xor(a4, 16); a4 += __shfl_xor(a4, 32);
    a5 += __shfl_xor(a5, 16); a5 += __shfl_xor(a5, 32);
    a6 += __shfl_xor(a6, 16); a6 += __shfl_xor(a6, 32);
    a7 += __shfl_xor(a7, 16); a7 += __shfl_xor(a7, 32);
    den += __shfl_xor(den, 16); den += __shfl_xor(den, 32);

    const float inv = 1.f / (den + 1e-8f);
    const float r0 = a0 * inv + rA.x;
    const float r1 = a1 * inv + rA.y;
    const float r2 = a2 * inv + rA.z;
    const float r3 = a3 * inv + rA.w;
    const float r4 = a4 * inv + rB.x;
    const float r5 = a5 * inv + rB.y;
    const float r6 = a6 * inv + rB.z;
    const float r7 = a7 * inv + rB.w;

    // LayerNorm: each dim appears 4x across the wave -> divide by 512
    float sum = ((r0 + r1) + (r2 + r3)) + ((r4 + r5) + (r6 + r7));
    float ssq = ((r0*r0 + r1*r1) + (r2*r2 + r3*r3)) + ((r4*r4 + r5*r5) + (r6*r6 + r7*r7));
    #pragma unroll
    for (int o = 1; o < 64; o <<= 1) {
        sum += __shfl_xor(sum, o);
        ssq += __shfl_xor(ssq, o);
    }
    const float mu   = sum * (1.f / 512.f);
    const float var  = ssq * (1.f / 512.f) - mu * mu;
    const float rstd = rsqrtf(var + 1e-6f);

    if (g == 0) {
        const float4 gA = *(const float4*)(gam + d0);
        const float4 gB = *(const float4*)(gam + d0 + 4);
        const float4 bA = *(const float4*)(bet + d0);
        const float4 bB = *(const float4*)(bet + d0 + 4);
        float4 oA, oB;
        oA.x = (r0 - mu) * rstd * gA.x + bA.x;
        oA.y = (r1 - mu) * rstd * gA.y + bA.y;
        oA.z = (r2 - mu) * rstd * gA.z + bA.z;
        oA.w = (r3 - mu) * rstd * gA.w + bA.w;
        oB.x = (r4 - mu) * rstd * gB.x + bB.x;
        oB.y = (r5 - mu) * rstd * gB.y + bB.y;
        oB.z = (r6 - mu) * rstd * gB.z + bB.z;
        oB.w = (r7 - mu) * rstd * gB.w + bB.w;
        *(float4*)(out + (size_t)node * D + d0)     = oA;
        *(float4*)(out + (size_t)node * D + d0 + 4) = oB;
    }
}

// ---------------------------------------------------------------------------
extern "C" void kernel_launch(void* const* d_in, const int* in_sizes, int n_in,
                              void* d_out, int out_size, void* d_ws, size_t ws_size,
                              hipStream_t stream)
{
    const float* emb  = (const float*)d_in[0];
    const int*   ei   = (const int*)d_in[1];
    const float* Wq   = (const float*)d_in[2];
    const float* Wk   = (const float*)d_in[3];
    const float* Wv   = (const float*)d_in[4];
    const float* gam  = (const float*)d_in[5];
    const float* bet  = (const float*)d_in[6];
    float*       out  = (float*)d_out;

    const int* rows = ei;
    const int* cols = ei + N_EDGES;

    char* ws = (char*)d_ws;
    auto alloc = [&](size_t bytes) {
        char* p = ws;
        ws += (bytes + 255) & ~size_t(255);
        return p;
    };
    ushort_t* Qh     = (ushort_t*)alloc((size_t)N_NODES * D * sizeof(ushort_t));
    ushort_t* KVh    = (ushort_t*)alloc((size_t)N_NODES * KVSTR * sizeof(ushort_t));
    ushort_t* WpAll  = (ushort_t*)alloc((size_t)3 * D * D * sizeof(ushort_t));
    int*      cnt    = (int*)alloc((size_t)N_NODES * sizeof(int));
    ushort_t* slots  = (ushort_t*)alloc((size_t)N_NODES * SCAP * sizeof(ushort_t));
    int*      cnt_g  = (int*)alloc((size_t)NBINS * NCH * sizeof(int));
    int*      sorted = (int*)alloc((size_t)NBINS * NCH * PCAP * sizeof(int));

    scatter_prep<<<3 + NCH, 256, 0, stream>>>(
        Wq, Wk, Wv, WpAll, rows, cols, sorted, cnt_g);

    gemm_build<<<QKV_BLOCKS + NBINS, 256, 0, stream>>>(
        emb, WpAll, Qh, KVh, sorted, cnt_g, cnt, slots);

    node_attn<<<(N_NODES * 64 + 255) / 256, 256, 0, stream>>>(
        Qh, KVh, emb, cnt, slots, gam, bet, out);
}

// Round 13
// 185.143 us; speedup vs baseline: 1.0814x; 1.0814x over previous
//
#include <hip/hip_runtime.h>
#include <hip/hip_fp16.h>
#include <cstdint>

#define N_NODES 50000
#define N_EDGES 800000
#define D 128
#define NCHUNK 400                                    // edge chunks
#define CHUNK_E 2000                                  // edges per chunk (400*2000 = N_EDGES)
#define NBINS 782                                     // coarse bins (64 nodes each)
#define BINCAP 1536                                   // slots per bin segment (mean 1024, sigma 32)
#define SCAP 64                                       // col slots per node
#define KVSTR 256                                     // halves per node in KV: 128 K + 128 V
#define QKV_BLOCKS ((N_NODES + 63) / 64)              // 782

typedef _Float16 half8 __attribute__((ext_vector_type(8)));
typedef _Float16 half2_t __attribute__((ext_vector_type(2)));
typedef __attribute__((ext_vector_type(4))) float float4v;
typedef unsigned short ushort_t;
typedef unsigned int uint_t;

__device__ __forceinline__ ushort_t f2h(float f) {
    return __half_as_ushort(__float2half(f));   // RNE hardware cvt
}
__device__ __forceinline__ half2_t u2h2(unsigned u) {
    union { unsigned u; half2_t h; } c; c.u = u; return c.h;
}

// ---------------------------------------------------------------------------
// k1: blocks 0..2 repack W fp32 -> fp16 B-fragment order; blocks 3..402 =
//     per-chunk histogram over 782 coarse bins (LDS atomics only).
// ---------------------------------------------------------------------------
__global__ __launch_bounds__(256) void prep_hist(
    const float* __restrict__ Wq, const float* __restrict__ Wk,
    const float* __restrict__ Wv, ushort_t* __restrict__ WpAll,
    const int* __restrict__ rows, int* __restrict__ hist_g)
{
    __shared__ int hist[NBINS];
    if (blockIdx.x < 3) {
        const float* W = (blockIdx.x == 0) ? Wq : (blockIdx.x == 1) ? Wk : Wv;
        ushort_t* Wp = WpAll + blockIdx.x * (D * D);
        for (int i = threadIdx.x; i < D * D; i += 256) {
            const int j    = i & 7;
            const int lane = (i >> 3) & 63;
            const int f    = i >> 9;
            const int kk = f >> 3, nt = f & 7;
            const int k = kk * 32 + (lane >> 4) * 8 + j;
            const int n = (lane & 15) * 8 + nt;     // permuted column order
            Wp[i] = f2h(W[k * D + n]);
        }
        return;
    }
    const int c = blockIdx.x - 3;
    for (int t = threadIdx.x; t < NBINS; t += 256) hist[t] = 0;
    __syncthreads();
    const int e0 = c * CHUNK_E;
    for (int i = threadIdx.x; i < CHUNK_E; i += 256)
        atomicAdd(&hist[rows[e0 + i] >> 6], 1);     // LDS-scope atomic
    __syncthreads();
    for (int t = threadIdx.x; t < NBINS; t += 256)
        hist_g[c * NBINS + t] = hist[t];
}

// ---------------------------------------------------------------------------
// k2: exclusive scan over chunks, one wave per bin (4 bins per block so the
//     strided hist reads share cache lines). prefix[c][b] = offset of chunk
//     c's first edge of bin b within the bin segment; binlen[b] = total.
// ---------------------------------------------------------------------------
__global__ __launch_bounds__(256) void scan(
    const int* __restrict__ hist_g, int* __restrict__ prefix_g,
    int* __restrict__ binlen)
{
    const int b    = blockIdx.x * 4 + (threadIdx.x >> 6);
    const int lane = threadIdx.x & 63;
    if (b >= NBINS) return;

    int v[7];
    int s = 0;
    const int c0 = lane * 7;                        // 64*7 = 448 >= 400
    #pragma unroll
    for (int j = 0; j < 7; ++j) {
        const int c = c0 + j;
        v[j] = (c < NCHUNK) ? hist_g[c * NBINS + b] : 0;
        s += v[j];
    }
    int incl = s;                                    // wave inclusive scan
    #pragma unroll
    for (int off = 1; off < 64; off <<= 1) {
        const int x = __shfl_up(incl, off);
        if (lane >= off) incl += x;
    }
    int run = incl - s;                              // exclusive
    #pragma unroll
    for (int j = 0; j < 7; ++j) {
        const int c = c0 + j;
        if (c < NCHUNK) prefix_g[c * NBINS + b] = run;
        run += v[j];
    }
    if (lane == 63) binlen[b] = incl;                // grand total for bin
}

// ---------------------------------------------------------------------------
// k3: blocks [0,NCHUNK): scatter edges into bin segments (ranks via LDS
//     histogram replay -> bijection onto [0, binlen), no device atomics).
//     blocks [NCHUNK, +QKV_BLOCKS): MFMA QKV GEMM, overlapped with scatter.
// ---------------------------------------------------------------------------
__global__ __launch_bounds__(256) void scatter_gemm(
    const int* __restrict__ rows, const int* __restrict__ cols,
    const int* __restrict__ prefix_g, int* __restrict__ sorted,
    const float* __restrict__ emb, const ushort_t* __restrict__ WpAll,
    ushort_t* __restrict__ Qh, ushort_t* __restrict__ KVh)
{
    __shared__ int pref[NBINS];
    __shared__ int h2[NBINS];

    if (blockIdx.x < NCHUNK) {
        const int c = blockIdx.x;
        for (int t = threadIdx.x; t < NBINS; t += 256) {
            pref[t] = prefix_g[c * NBINS + t];
            h2[t] = 0;
        }
        __syncthreads();
        const int e0 = c * CHUNK_E;
        for (int i = threadIdx.x; i < CHUNK_E; i += 256) {
            const int row = rows[e0 + i];
            const int col = cols[e0 + i];
            const int bin = row >> 6;
            const int r = atomicAdd(&h2[bin], 1);    // LDS-scope atomic
            const int p = pref[bin] + r;
            if (p < BINCAP)
                sorted[bin * BINCAP + p] = ((row & 63) << 16) | col;  // col < 2^16
        }
        return;
    }

    const int blk  = blockIdx.x - NCHUNK;
    const int t    = threadIdx.x;
    const int wave = t >> 6;
    const int lane = t & 63;
    const int row0 = blk * 64 + wave * 16;
    const int m    = lane & 15;
    const int q    = lane >> 4;

    // A fragments: loaded once, reused for Q,K,V
    const int arow = min(row0 + m, N_NODES - 1);
    const float* abase = emb + (size_t)arow * D + q * 8;
    half8 a[4];
    #pragma unroll
    for (int kk = 0; kk < 4; ++kk) {
        const float4 f0 = *(const float4*)(abase + kk * 32);
        const float4 f1 = *(const float4*)(abase + kk * 32 + 4);
        a[kk][0] = (_Float16)f0.x; a[kk][1] = (_Float16)f0.y;
        a[kk][2] = (_Float16)f0.z; a[kk][3] = (_Float16)f0.w;
        a[kk][4] = (_Float16)f1.x; a[kk][5] = (_Float16)f1.y;
        a[kk][6] = (_Float16)f1.z; a[kk][7] = (_Float16)f1.w;
    }

    for (int y = 0; y < 3; ++y) {
        const ushort_t* Wp = WpAll + y * (D * D);

        float4v acc[8];
        #pragma unroll
        for (int nt = 0; nt < 8; ++nt) acc[nt] = (float4v){0.f, 0.f, 0.f, 0.f};

        #pragma unroll
        for (int kk = 0; kk < 4; ++kk) {
            #pragma unroll
            for (int nt = 0; nt < 8; ++nt) {
                const half8 bfr = *(const half8*)(Wp + ((kk * 8 + nt) * 64 + lane) * 8);
                acc[nt] = __builtin_amdgcn_mfma_f32_16x16x32_f16(a[kk], bfr, acc[nt], 0, 0, 0);
            }
        }

        #pragma unroll
        for (int r = 0; r < 4; ++r) {
            const int row = row0 + q * 4 + r;
            if (row < N_NODES) {
                ushort_t pk[8];
                #pragma unroll
                for (int nt = 0; nt < 8; ++nt) pk[nt] = f2h(acc[nt][r]);
                ushort_t* dst =
                    (y == 0) ? (Qh  + (size_t)row * D + m * 8)
                  : (y == 1) ? (KVh + (size_t)row * KVSTR + m * 8)
                             : (KVh + (size_t)row * KVSTR + 128 + m * 8);
                *(int4*)dst = *(const int4*)pk;
            }
        }
    }
}

// ---------------------------------------------------------------------------
// k4: one block per bin: build per-node ushort col lists from the bin
//     segment in LDS (LDS atomics, ~1k edges) -> coalesced slots + cnt.
// ---------------------------------------------------------------------------
__global__ __launch_bounds__(256) void build(
    const int* __restrict__ sorted, const int* __restrict__ binlen,
    int* __restrict__ cnt, ushort_t* __restrict__ slots)
{
    __shared__ ushort_t sl[64 * SCAP];   // 8 KB
    __shared__ int scnt[64];

    const int b = blockIdx.x;
    if (threadIdx.x < 64) scnt[threadIdx.x] = 0;
    __syncthreads();
    const int len = min(binlen[b], BINCAP);
    for (int i = threadIdx.x; i < len; i += 256) {
        const int p  = sorted[b * BINCAP + i];
        const int rl = p >> 16;
        const int pos = atomicAdd(&scnt[rl], 1);     // LDS-scope atomic
        if (pos < SCAP) sl[rl * SCAP + pos] = (ushort_t)(p & 0xFFFF);
    }
    __syncthreads();
    const int node0 = b * 64;
    const uint_t* slu = (const uint_t*)sl;
    uint_t* out_u = (uint_t*)(slots + (size_t)node0 * SCAP);
    for (int t = threadIdx.x; t < 2048; t += 256) {  // 32 uints per node
        const int node = node0 + (t >> 5);
        if (node < N_NODES) out_u[t] = slu[t];
    }
    if (threadIdx.x < 64) {
        const int node = node0 + threadIdx.x;
        if (node < N_NODES) cnt[node] = scnt[threadIdx.x];
    }
}

// ---------------------------------------------------------------------------
// k5: Node attention (the proven 61 µs kernel): one wave per node; lane owns
// 8 dims; 16 lanes per edge, 4 edge-groups; x2 unroll -> 8 edges in flight.
// Ushort slot line; cols via bpermute; K and V are one 512 B KVh record.
// ---------------------------------------------------------------------------
__global__ __launch_bounds__(256) void node_attn(
    const ushort_t* __restrict__ Qh, const ushort_t* __restrict__ KVh,
    const float* __restrict__ emb,
    const int* __restrict__ cnt, const ushort_t* __restrict__ slots,
    const float* __restrict__ gam, const float* __restrict__ bet,
    float* __restrict__ out)
{
    const int node = (int)((blockIdx.x * blockDim.x + threadIdx.x) >> 6);
    if (node >= N_NODES) return;
    const int lane = threadIdx.x & 63;
    const int g    = lane >> 4;          // edge group 0..3
    const int l4   = lane & 15;          // dim-lane within edge
    const int d0   = l4 * 8;             // first of 8 owned dims

    // full slot line in registers: lane j holds col j
    const int slot = (int)slots[(size_t)node * SCAP + lane];
    const int deg  = min(cnt[node], SCAP);

    const uint4 qw = *(const uint4*)(Qh + (size_t)node * D + d0);
    const half2_t q01 = u2h2(qw.x), q23 = u2h2(qw.y);
    const half2_t q45 = u2h2(qw.z), q67 = u2h2(qw.w);

    // residual load hoisted above the loop (independent; hides latency)
    const float4 rA = *(const float4*)(emb + (size_t)node * D + d0);
    const float4 rB = *(const float4*)(emb + (size_t)node * D + d0 + 4);

    float a0=0.f,a1=0.f,a2=0.f,a3=0.f,a4=0.f,a5=0.f,a6=0.f,a7=0.f,den=0.f;

    int i = 0;
    for (; i + 8 <= deg; i += 8) {
        const int cA = __shfl(slot, i + g);
        const int cB = __shfl(slot, i + 4 + g);
        const ushort_t* kvA = KVh + (size_t)cA * KVSTR + d0;
        const ushort_t* kvB = KVh + (size_t)cB * KVSTR + d0;
        const uint4 kA = *(const uint4*)(kvA);
        const uint4 vA = *(const uint4*)(kvA + 128);
        const uint4 kB = *(const uint4*)(kvB);
        const uint4 vB = *(const uint4*)(kvB + 128);

        float pA = __builtin_amdgcn_fdot2(q01, u2h2(kA.x), 0.f, false);
        pA = __builtin_amdgcn_fdot2(q23, u2h2(kA.y), pA, false);
        pA = __builtin_amdgcn_fdot2(q45, u2h2(kA.z), pA, false);
        pA = __builtin_amdgcn_fdot2(q67, u2h2(kA.w), pA, false);
        float pB = __builtin_amdgcn_fdot2(q01, u2h2(kB.x), 0.f, false);
        pB = __builtin_amdgcn_fdot2(q23, u2h2(kB.y), pB, false);
        pB = __builtin_amdgcn_fdot2(q45, u2h2(kB.z), pB, false);
        pB = __builtin_amdgcn_fdot2(q67, u2h2(kB.w), pB, false);
        pA += __shfl_xor(pA, 1);
        pB += __shfl_xor(pB, 1);
        const float wA = __expf(fminf(10.f, fmaxf(-10.f, pA)));
        const float wB = __expf(fminf(10.f, fmaxf(-10.f, pB)));
        den += wA + wB;

        const half2_t vA01 = u2h2(vA.x), vA23 = u2h2(vA.y);
        const half2_t vA45 = u2h2(vA.z), vA67 = u2h2(vA.w);
        const half2_t vB01 = u2h2(vB.x), vB23 = u2h2(vB.y);
        const half2_t vB45 = u2h2(vB.z), vB67 = u2h2(vB.w);
        a0 += wA * (float)vA01[0] + wB * (float)vB01[0];
        a1 += wA * (float)vA01[1] + wB * (float)vB01[1];
        a2 += wA * (float)vA23[0] + wB * (float)vB23[0];
        a3 += wA * (float)vA23[1] + wB * (float)vB23[1];
        a4 += wA * (float)vA45[0] + wB * (float)vB45[0];
        a5 += wA * (float)vA45[1] + wB * (float)vB45[1];
        a6 += wA * (float)vA67[0] + wB * (float)vB67[0];
        a7 += wA * (float)vA67[1] + wB * (float)vB67[1];
    }
    for (; i < deg; i += 4) {
        const int idx = i + g;
        const int c = __shfl(slot, (idx < deg) ? idx : (deg - 1));
        const ushort_t* kv = KVh + (size_t)c * KVSTR + d0;
        const uint4 kk = *(const uint4*)(kv);
        const uint4 vv = *(const uint4*)(kv + 128);
        float p = __builtin_amdgcn_fdot2(q01, u2h2(kk.x), 0.f, false);
        p = __builtin_amdgcn_fdot2(q23, u2h2(kk.y), p, false);
        p = __builtin_amdgcn_fdot2(q45, u2h2(kk.z), p, false);
        p = __builtin_amdgcn_fdot2(q67, u2h2(kk.w), p, false);
        p += __shfl_xor(p, 1);
        float w = __expf(fminf(10.f, fmaxf(-10.f, p)));
        w = (idx < deg) ? w : 0.f;
        den += w;
        const half2_t v01 = u2h2(vv.x), v23 = u2h2(vv.y);
        const half2_t v45 = u2h2(vv.z), v67 = u2h2(vv.w);
        a0 += w * (float)v01[0]; a1 += w * (float)v01[1];
        a2 += w * (float)v23[0]; a3 += w * (float)v23[1];
        a4 += w * (float)v45[0]; a5 += w * (float)v45[1];
        a6 += w * (float)v67[0]; a7 += w * (float)v67[1];
    }

    // fold the 4 edge-groups
    a0 += __shfl_xor(a0, 16); a0 += __shfl_xor(a0, 32);
    a1 += __shfl_xor(a1, 16); a1 += __shfl_xor(a1, 32);
    a2 += __shfl_xor(a2, 16); a2 += __shfl_xor(a2, 32);
    a3 += __shfl_xor(a3, 16); a3 += __shfl_xor(a3, 32);
    a4 += __shfl_xor(a4, 16); a4 += __shfl_xor(a4, 32);
    a5 += __shfl_xor(a5, 16); a5 += __shfl_xor(a5, 32);
    a6 += __shfl_xor(a6, 16); a6 += __shfl_xor(a6, 32);
    a7 += __shfl_xor(a7, 16); a7 += __shfl_xor(a7, 32);
    den += __shfl_xor(den, 16); den += __shfl_xor(den, 32);

    const float inv = 1.f / (den + 1e-8f);
    const float r0 = a0 * inv + rA.x;
    const float r1 = a1 * inv + rA.y;
    const float r2 = a2 * inv + rA.z;
    const float r3 = a3 * inv + rA.w;
    const float r4 = a4 * inv + rB.x;
    const float r5 = a5 * inv + rB.y;
    const float r6 = a6 * inv + rB.z;
    const float r7 = a7 * inv + rB.w;

    // LayerNorm: each dim appears 4x across the wave -> divide by 512
    float sum = ((r0 + r1) + (r2 + r3)) + ((r4 + r5) + (r6 + r7));
    float ssq = ((r0*r0 + r1*r1) + (r2*r2 + r3*r3)) + ((r4*r4 + r5*r5) + (r6*r6 + r7*r7));
    #pragma unroll
    for (int o = 1; o < 64; o <<= 1) {
        sum += __shfl_xor(sum, o);
        ssq += __shfl_xor(ssq, o);
    }
    const float mu   = sum * (1.f / 512.f);
    const float var  = ssq * (1.f / 512.f) - mu * mu;
    const float rstd = rsqrtf(var + 1e-6f);

    if (g == 0) {
        const float4 gA = *(const float4*)(gam + d0);
        const float4 gB = *(const float4*)(gam + d0 + 4);
        const float4 bA = *(const float4*)(bet + d0);
        const float4 bB = *(const float4*)(bet + d0 + 4);
        float4 oA, oB;
        oA.x = (r0 - mu) * rstd * gA.x + bA.x;
        oA.y = (r1 - mu) * rstd * gA.y + bA.y;
        oA.z = (r2 - mu) * rstd * gA.z + bA.z;
        oA.w = (r3 - mu) * rstd * gA.w + bA.w;
        oB.x = (r4 - mu) * rstd * gB.x + bB.x;
        oB.y = (r5 - mu) * rstd * gB.y + bB.y;
        oB.z = (r6 - mu) * rstd * gB.z + bB.z;
        oB.w = (r7 - mu) * rstd * gB.w + bB.w;
        *(float4*)(out + (size_t)node * D + d0)     = oA;
        *(float4*)(out + (size_t)node * D + d0 + 4) = oB;
    }
}

// ---------------------------------------------------------------------------
extern "C" void kernel_launch(void* const* d_in, const int* in_sizes, int n_in,
                              void* d_out, int out_size, void* d_ws, size_t ws_size,
                              hipStream_t stream)
{
    const float* emb  = (const float*)d_in[0];
    const int*   ei   = (const int*)d_in[1];
    const float* Wq   = (const float*)d_in[2];
    const float* Wk   = (const float*)d_in[3];
    const float* Wv   = (const float*)d_in[4];
    const float* gam  = (const float*)d_in[5];
    const float* bet  = (const float*)d_in[6];
    float*       out  = (float*)d_out;

    const int* rows = ei;
    const int* cols = ei + N_EDGES;

    char* ws = (char*)d_ws;
    auto alloc = [&](size_t bytes) {
        char* p = ws;
        ws += (bytes + 255) & ~size_t(255);
        return p;
    };
    ushort_t* Qh     = (ushort_t*)alloc((size_t)N_NODES * D * sizeof(ushort_t));
    ushort_t* KVh    = (ushort_t*)alloc((size_t)N_NODES * KVSTR * sizeof(ushort_t));
    ushort_t* WpAll  = (ushort_t*)alloc((size_t)3 * D * D * sizeof(ushort_t));
    int*      cnt    = (int*)alloc((size_t)N_NODES * sizeof(int));
    ushort_t* slots  = (ushort_t*)alloc((size_t)N_NODES * SCAP * sizeof(ushort_t));
    int*      hist_g = (int*)alloc((size_t)NCHUNK * NBINS * sizeof(int));
    int*      pref_g = (int*)alloc((size_t)NCHUNK * NBINS * sizeof(int));
    int*      binlen = (int*)alloc((size_t)NBINS * sizeof(int));
    int*      sorted = (int*)alloc((size_t)NBINS * BINCAP * sizeof(int));

    prep_hist<<<3 + NCHUNK, 256, 0, stream>>>(Wq, Wk, Wv, WpAll, rows, hist_g);

    scan<<<(NBINS + 3) / 4, 256, 0, stream>>>(hist_g, pref_g, binlen);

    scatter_gemm<<<NCHUNK + QKV_BLOCKS, 256, 0, stream>>>(
        rows, cols, pref_g, sorted, emb, WpAll, Qh, KVh);

    build<<<NBINS, 256, 0, stream>>>(sorted, binlen, cnt, slots);

    node_attn<<<(N_NODES * 64 + 255) / 256, 256, 0, stream>>>(
        Qh, KVh, emb, cnt, slots, gam, bet, out);
}